// Round 1
// baseline (619.751 us; speedup 1.0000x reference)
//
#include <hip/hip_runtime.h>
#include <hip/hip_bf16.h>

#define HW 65536
#define KHALF 288        // keys per block (split-K half)
#define KPAD2 328        // Vt row stride in shorts: 164 words, 164%32=4 -> 2-way max (free)

typedef __attribute__((ext_vector_type(8))) short bf8;
typedef __attribute__((ext_vector_type(4))) float f4;

__device__ __forceinline__ unsigned short f2b(float x) {   // RNE float->bf16
  unsigned int u = __float_as_uint(x);
  unsigned int r = (u + 0x7fff + ((u >> 16) & 1)) >> 16;
  return (unsigned short)r;
}
__device__ __forceinline__ unsigned int pk2(float lo, float hi) {  // trunc pack 2xbf16
  return (__float_as_uint(hi) & 0xffff0000u) | (__float_as_uint(lo) >> 16);
}
__device__ __forceinline__ float b2f(unsigned short u) {
  return __uint_as_float(((unsigned int)u) << 16);
}
__device__ __forceinline__ float ex2(float x) { return __builtin_amdgcn_exp2f(x); }

// ================= device bodies =================
__device__ __forceinline__ void stem_front_body(
    int bx, int t, const float* __restrict__ depth,
    const float* __restrict__ cw1, const float* __restrict__ cb1,
    const float* __restrict__ cw2, const float* __restrict__ cb2,
    float* __restrict__ t2) {
  int p = bx * 256 + t;
  int y = p >> 8, x = p & 255;
  float in9[9];
#pragma unroll
  for (int ky = 0; ky < 3; ky++)
#pragma unroll
    for (int kx = 0; kx < 3; kx++) {
      int yy = y + ky - 1, xx = x + kx - 1;
      bool ok = ((unsigned)yy < 256u) && ((unsigned)xx < 256u);
      in9[ky*3+kx] = ok ? depth[yy*256+xx] : 0.f;
    }
  float t1[8];
#pragma unroll
  for (int o = 0; o < 8; o++) {
    float s = cb1[o];
#pragma unroll
    for (int i = 0; i < 9; i++) s += in9[i] * cw1[o*9+i];
    t1[o] = fmaxf(s, 0.f);
  }
#pragma unroll
  for (int o = 0; o < 16; o++) {
    float s = cb2[o];
#pragma unroll
    for (int ci = 0; ci < 8; ci++) s += t1[ci] * cw2[o*8+ci];
    t2[o*HW + p] = fmaxf(s, 0.f);
  }
}

// packed bf16 bias: word W(hd,qt,kt2g,quad,q,r) = pack(bias(key+16,q), bias(key,q))
// with key = kt2g*32 + quad*4 + r ; scale 1/ln2, NO -8 shift (cancels in softmax)
__device__ __forceinline__ void bias_pk_body(
    int bx, int t, const int* __restrict__ rpi,
    const float* __restrict__ rpb, unsigned int* __restrict__ biasPk) {
  int idx = bx*256 + t;        // 576*256 = 147456 exact
  int hd = idx / 73728;
  int rem = idx - hd*73728;
  int qt = rem / 4608;
  int r2 = rem - qt*4608;
  int kt2 = r2 >> 8;
  int w8 = r2 & 255;
  int quad = w8 >> 6, q = (w8 >> 2) & 15, r = w8 & 3;
  int klo = kt2*32 + quad*4 + r;
  int qq = qt*16 + q;
  float lo = rpb[rpi[qq*576 + klo]*2 + hd] * 1.44269504f;
  float hi = rpb[rpi[qq*576 + klo + 16]*2 + hd] * 1.44269504f;
  biasPk[idx] = ((unsigned int)f2b(hi) << 16) | (unsigned int)f2b(lo);
}

// 48-output LN(+IN) matmul slab, weights via uniform (s_load) global reads.
// role 0: src=x      slice0 -> q1[0:32) + kv2[0:16)
// role 1: src=x      slice1 -> kv2[16:64)
// role 2: src=IN(t4) slice0 -> q2[0:32) + kv1[0:16)
// role 3: src=IN(t4) slice1 -> kv1[16:64)
__device__ __forceinline__ void lnmm48_body(
    int role, int bx, int t, float* as_, float* bbs_,
    const float* __restrict__ x, const float* __restrict__ t4,
    const float* __restrict__ part,
    const float* __restrict__ ig, const float* __restrict__ ib,
    const float* __restrict__ n1g, const float* __restrict__ n1b,
    const float* __restrict__ wq, const float* __restrict__ bq,
    const float* __restrict__ wkv, const float* __restrict__ bkv,
    float* __restrict__ q1, float* __restrict__ kv1,
    float* __restrict__ q2, float* __restrict__ kv2) {
  bool ain = role >= 2;
  int slice = role & 1;
  const float* src = ain ? t4 : x;
  float* dq  = ain ? q2 : q1;
  float* dkv = ain ? kv1 : kv2;
  if (ain) {
    if (t < 32) {
      float s = 0.f, ss = 0.f;
#pragma unroll
      for (int k = 0; k < 16; k++) { s += part[t*16+k]; ss += part[512 + t*16+k]; }
      float m = s * (1.f/65536.f);
      float var = ss * (1.f/65536.f) - m*m;
      float a = rsqrtf(var + 1e-5f) * ig[t];
      as_[t] = a; bbs_[t] = ib[t] - m*a;
    }
    __syncthreads();
  }
  int p = bx*256 + t;
  float v[32]; float s = 0.f;
  if (ain) {
#pragma unroll
    for (int c = 0; c < 32; c++) { v[c] = src[c*HW+p]*as_[c] + bbs_[c]; s += v[c]; }
  } else {
#pragma unroll
    for (int c = 0; c < 32; c++) { v[c] = src[c*HW+p]; s += v[c]; }
  }
  float m = s * 0.03125f;
  float ss = 0.f;
#pragma unroll
  for (int c = 0; c < 32; c++) { float d = v[c]-m; ss += d*d; }
  float rs = rsqrtf(ss*0.03125f + 1e-5f);
  float acc[48];
  if (slice == 0) {
#pragma unroll
    for (int j = 0; j < 32; j++) acc[j] = bq[j];
#pragma unroll
    for (int j = 0; j < 16; j++) acc[32+j] = bkv[j];
#pragma unroll
    for (int c = 0; c < 32; c++) {
      float ln = (v[c]-m)*rs*n1g[c] + n1b[c];
#pragma unroll
      for (int j = 0; j < 32; j++) acc[j] += ln*wq[c*32+j];      // uniform -> s_load
#pragma unroll
      for (int j = 0; j < 16; j++) acc[32+j] += ln*wkv[c*64+j];  // uniform -> s_load
    }
#pragma unroll
    for (int j = 0; j < 32; j++) dq[j*HW+p] = acc[j];
#pragma unroll
    for (int j = 0; j < 16; j++) dkv[j*HW+p] = acc[32+j];
  } else {
#pragma unroll
    for (int j = 0; j < 48; j++) acc[j] = bkv[16+j];
#pragma unroll
    for (int c = 0; c < 32; c++) {
      float ln = (v[c]-m)*rs*n1g[c] + n1b[c];
#pragma unroll
      for (int j = 0; j < 48; j++) acc[j] += ln*wkv[c*64+16+j];  // uniform -> s_load
    }
#pragma unroll
    for (int j = 0; j < 48; j++) dkv[(16+j)*HW+p] = acc[j];
  }
}

// ================= kernels =================
// flat mega-launch: [0,256) stem | [256,832) biasPk | [832,1344) lnmm48 roles 0,1
__global__ __launch_bounds__(256, 2) void k_misc(
    const float* __restrict__ depth,
    const float* __restrict__ cw1, const float* __restrict__ cb1,
    const float* __restrict__ cw2, const float* __restrict__ cb2,
    float* __restrict__ t2,
    const int* __restrict__ rpi, const float* __restrict__ rpb,
    unsigned int* __restrict__ biasPk,
    const float* __restrict__ x, const float* __restrict__ t4,
    const float* __restrict__ part,
    const float* __restrict__ ig, const float* __restrict__ ib,
    const float* __restrict__ n1g, const float* __restrict__ n1b,
    const float* __restrict__ wq, const float* __restrict__ bq,
    const float* __restrict__ wkv, const float* __restrict__ bkv,
    float* q1, float* kv1, float* q2, float* kv2) {
  __shared__ float as_[32], bbs_[32];
  int id = blockIdx.x, t = threadIdx.x;
  if (id < 256) { stem_front_body(id, t, depth, cw1, cb1, cw2, cb2, t2); return; }
  if (id < 832) { bias_pk_body(id - 256, t, rpi, rpb, biasPk); return; }
  int r = id - 832;
  lnmm48_body(r >> 8, r & 255, t, as_, bbs_,
              x, t4, part, ig, ib, n1g, n1b, wq, bq, wkv, bkv, q1, kv1, q2, kv2);
}

__global__ __launch_bounds__(256, 2) void k_lnmmB2(
    const float* __restrict__ x, const float* __restrict__ t4,
    const float* __restrict__ part,
    const float* __restrict__ ig, const float* __restrict__ ib,
    const float* __restrict__ n1g, const float* __restrict__ n1b,
    const float* __restrict__ wq, const float* __restrict__ bq,
    const float* __restrict__ wkv, const float* __restrict__ bkv,
    float* q1, float* kv1, float* q2, float* kv2) {
  __shared__ float as_[32], bbs_[32];
  lnmm48_body(2 + blockIdx.y, blockIdx.x, threadIdx.x, as_, bbs_,
              x, t4, part, ig, ib, n1g, n1b, wq, bq, wkv, bkv, q1, kv1, q2, kv2);
}

__global__ __launch_bounds__(256) void k_conv3(
    const float* __restrict__ t2, const float* __restrict__ cw3,
    const float* __restrict__ cb3, float* __restrict__ t3) {
  int t = threadIdx.x;
  int p = blockIdx.x*256 + t;
  int og = blockIdx.y;
  int y = p >> 8, x = p & 255;
  float acc[4];
#pragma unroll
  for (int o = 0; o < 4; o++) acc[o] = cb3[og*4+o];
#pragma unroll 1
  for (int tap = 0; tap < 9; tap++) {
    int ky = tap/3 - 1, kx = tap - (tap/3)*3 - 1;
    int yy = y+ky, xx = x+kx;
    bool ok = ((unsigned)yy < 256u) && ((unsigned)xx < 256u);
    int pp = yy*256+xx;
#pragma unroll
    for (int ci = 0; ci < 16; ci++) {
      float v = ok ? t2[ci*HW+pp] : 0.f;
#pragma unroll
      for (int o = 0; o < 4; o++)
        acc[o] += v * cw3[(og*4+o)*144 + ci*9 + tap];   // uniform -> s_load
    }
  }
#pragma unroll
  for (int o = 0; o < 4; o++) t3[(og*4+o)*HW+p] = fmaxf(acc[o], 0.f);
}

__global__ __launch_bounds__(256) void k_conv4(
    const float* __restrict__ t3, const float* __restrict__ cw4,
    const float* __restrict__ cb4, float* __restrict__ t4) {
  int t = threadIdx.x;
  int p = blockIdx.x*256 + t;
  int og = blockIdx.y;           // 8 outputs per group
  float v[16];
#pragma unroll
  for (int ci = 0; ci < 16; ci++) v[ci] = t3[ci*HW+p];
#pragma unroll
  for (int o = 0; o < 8; o++) {
    int oo = og*8 + o;
    float s = cb4[oo];
#pragma unroll
    for (int ci = 0; ci < 16; ci++) s += v[ci]*cw4[oo*16+ci];
    t4[oo*HW+p] = s;
  }
}

__global__ __launch_bounds__(256) void k_instats1(const float* __restrict__ t4,
                                                  float* __restrict__ part) {
  int c = blockIdx.x >> 4, seg = blockIdx.x & 15;   // 512 blocks
  const float4* src = (const float4*)(t4 + c*HW + seg*4096);
  float s = 0.f, ss = 0.f;
  for (int i = threadIdx.x; i < 1024; i += 256) {
    float4 v = src[i];
    s  += v.x + v.y + v.z + v.w;
    ss += v.x*v.x + v.y*v.y + v.z*v.z + v.w*v.w;
  }
#pragma unroll
  for (int off = 32; off > 0; off >>= 1) {
    s  += __shfl_down(s, off, 64);
    ss += __shfl_down(ss, off, 64);
  }
  __shared__ float sh[8];
  int wid = threadIdx.x >> 6;
  if ((threadIdx.x & 63) == 0) { sh[wid] = s; sh[4+wid] = ss; }
  __syncthreads();
  if (threadIdx.x == 0) {
    part[blockIdx.x]       = sh[0]+sh[1]+sh[2]+sh[3];
    part[512 + blockIdx.x] = sh[4]+sh[5]+sh[6]+sh[7];
  }
}

// ---------------- MFMA attention: split-K (288 keys/block), 8 blocks/CU ----------------
// y: sel = y>>1 (ocab), half = y&1 (key half). Partial o (bf16) + partial l (bf16) out.
__global__ __launch_bounds__(256, 8) void k_attn(
    const float* __restrict__ qA, const float* __restrict__ kvA,
    unsigned short* __restrict__ paoA, unsigned short* __restrict__ plA,
    const float* __restrict__ qB, const float* __restrict__ kvB,
    unsigned short* __restrict__ paoB, unsigned short* __restrict__ plB,
    const unsigned int* __restrict__ biasPk) {
  __shared__ __align__(16) unsigned short Ks[KHALF*16];   // [key][d]  9216B
  __shared__ __align__(16) unsigned short Vt[16*KPAD2];   // [d][key-permuted] 10496B

  int sel = blockIdx.y >> 1, half = blockIdx.y & 1;
  const float* q  = sel ? qB  : qA;
  const float* kv = sel ? kvB : kvA;
  unsigned short* pao = sel ? paoB : paoA;
  unsigned short* pl  = sel ? plB  : plA;

  // XCD swizzle: contiguous window stripes per XCD for kv-overlap L2 reuse
  int id = blockIdx.x;                       // 0..511
  int lin = ((id & 7) << 6) | (id >> 3);
  int wi = lin >> 1, hd = lin & 1;
  int wy = wi >> 4, wx = wi & 15;
  int t = threadIdx.x;
  int by = wy*16 - 4 + half*12, bx = wx*16 - 4;
  int kbase = hd*16*HW, vbase = (32 + hd*16)*HW;

  int wave = t >> 6, lane = t & 63;
  int quad = lane >> 4, l16 = lane & 15;
  const bf8 zero8 = {0,0,0,0,0,0,0,0};

  // --- Q fragments: direct register gather (no LDS, no barrier needed)
  bf8 qf[4];
#pragma unroll
  for (int qi = 0; qi < 4; qi++) {
    int qt = wave*4 + qi;
    if (quad < 2) {
      int prow = (wy*16 + qt)*256 + wx*16 + l16;
      unsigned short qtmp[8];
#pragma unroll
      for (int j = 0; j < 8; j++)
        qtmp[j] = f2b(q[(hd*16 + quad*8 + j)*HW + prow] * 0.360673503f); // 0.25/ln2
      qf[qi] = *(const bf8*)qtmp;
    } else {
      qf[qi] = zero8;
    }
  }

  // --- stage K (row-major) and V (transposed, slot-permuted), 288 keys = 12 rows of 24
  for (int e = t; e < KHALF; e += 256) {
    int dy = e / 24, dx = e - dy*24;
    int yy = by + dy, xx = bx + dx;
    bool ok = ((unsigned)yy < 256u) && ((unsigned)xx < 256u);
    int pp = yy*256 + xx;
    int off = e & 31;
    int ppos = ((off & 12) << 1) + ((off >> 4) << 2) + (off & 3);
    int vcol = (e & ~31) + ppos;
    unsigned short tk[16];
#pragma unroll
    for (int i = 0; i < 16; i++) {
      float kvl = ok ? kv[kbase + i*HW + pp] : 0.f;
      float vvl = ok ? kv[vbase + i*HW + pp] : 0.f;
      tk[i] = f2b(kvl);
      Vt[i*KPAD2 + vcol] = f2b(vvl);
    }
    *(uint4*)&Ks[e*16]     = *(uint4*)&tk[0];
    *(uint4*)&Ks[e*16 + 8] = *(uint4*)&tk[8];
  }
  __syncthreads();

  f4 oacc[4];
  float lr[4];
  unsigned int bboff[4];
#pragma unroll
  for (int qi = 0; qi < 4; qi++) {
    int qt = wave*4 + qi;
    oacc[qi] = (f4){0.f,0.f,0.f,0.f};
    lr[qi] = 0.f;
    bboff[qi] = (unsigned)((hd*16 + qt)*4608 + half*2304 + quad*64 + l16*4);
  }

#pragma unroll 2
  for (int kt2 = 0; kt2 < 9; kt2++) {
    int k0 = kt2 * 32;
    bf8 kf0 = zero8, kf1 = zero8;
    if (quad < 2) {
      kf0 = *(const bf8*)&Ks[(k0 + l16)*16 + quad*8];
      kf1 = *(const bf8*)&Ks[(k0 + 16 + l16)*16 + quad*8];
    }
    bf8 vf = *(const bf8*)&Vt[l16*KPAD2 + k0 + quad*8];
    __builtin_amdgcn_s_setprio(1);
#pragma unroll
    for (int qi = 0; qi < 4; qi++) {
      union { uint4 v; unsigned int u[4]; } bw;
      bw.v = *(const uint4*)&biasPk[bboff[qi] + kt2*256];
      f4 b0, b1;
#pragma unroll
      for (int r = 0; r < 4; r++) {
        unsigned int u = bw.u[r];
        b0[r] = __uint_as_float(u << 16);
        b1[r] = __uint_as_float(u & 0xffff0000u);
      }
      f4 s0 = __builtin_amdgcn_mfma_f32_16x16x32_bf16(kf0, qf[qi], b0, 0, 0, 0);
      f4 s1 = __builtin_amdgcn_mfma_f32_16x16x32_bf16(kf1, qf[qi], b1, 0, 0, 0);
      float p0[4], p1[4];
#pragma unroll
      for (int r = 0; r < 4; r++) {
        p0[r] = ex2(s0[r]);
        p1[r] = ex2(s1[r]);
        lr[qi] += p0[r] + p1[r];
      }
      union { unsigned int u[4]; bf8 v; } P;
      P.u[0] = pk2(p0[0], p0[1]); P.u[1] = pk2(p0[2], p0[3]);
      P.u[2] = pk2(p1[0], p1[1]); P.u[3] = pk2(p1[2], p1[3]);
      oacc[qi] = __builtin_amdgcn_mfma_f32_16x16x32_bf16(P.v, vf, oacc[qi], 0, 0, 0);
    }
    __builtin_amdgcn_s_setprio(0);
  }
#pragma unroll
  for (int qi = 0; qi < 4; qi++) {
    lr[qi] += __shfl_xor(lr[qi], 16, 64);
    lr[qi] += __shfl_xor(lr[qi], 32, 64);
  }
#pragma unroll
  for (int qi = 0; qi < 4; qi++) {
    int qt = wave*4 + qi;
#pragma unroll
    for (int r = 0; r < 4; r++) {
      int col = quad*4 + r;
      pao[(half*32 + hd*16 + l16)*HW + (wy*16 + qt)*256 + wx*16 + col] = f2b(oacc[qi][r]);
    }
    if (quad == 0) {
      pl[(half*2 + hd)*HW + (wy*16 + qt)*256 + wx*16 + l16] = f2b(lr[qi]);
    }
  }
}

// ---------------- merge partials + proj + shortcut + LN + MLP (s_load weights) ----------------
__global__ __launch_bounds__(256) void k_projmlp(
    const unsigned short* __restrict__ pao1, const unsigned short* __restrict__ pl1,
    const unsigned short* __restrict__ pao2, const unsigned short* __restrict__ pl2,
    const float* __restrict__ x, const float* __restrict__ t4,
    const float* __restrict__ part,
    const float* __restrict__ ig, const float* __restrict__ ib,
    const float* __restrict__ wp, const float* __restrict__ bp,
    const float* __restrict__ n2g, const float* __restrict__ n2b,
    const float* __restrict__ mw1, const float* __restrict__ mb1,
    const float* __restrict__ mw2, const float* __restrict__ mb2,
    float* __restrict__ o1, float* __restrict__ o2) {
  int oc = blockIdx.y;
  const unsigned short* pao = oc ? pao2 : pao1;
  const unsigned short* pl  = oc ? pl2  : pl1;
  float* dst = oc ? o2 : o1;
  __shared__ float as_[32], bbs_[32];
  int t = threadIdx.x;
  if (t < 32) {
    float s = 0.f, ss = 0.f;
#pragma unroll
    for (int k = 0; k < 16; k++) { s += part[t*16+k]; ss += part[512 + t*16+k]; }
    float m = s * (1.f/65536.f);
    float var = ss * (1.f/65536.f) - m*m;
    float a = rsqrtf(var + 1e-5f) * ig[t];
    as_[t] = a; bbs_[t] = ib[t] - m*a;
  }
  __syncthreads();
  int p = blockIdx.x*256 + t;
  // merge split-K halves: o = (oA + oB) / (lA + lB), per head
  float inv0 = 1.f / (b2f(pl[p])      + b2f(pl[2*HW+p]));
  float inv1 = 1.f / (b2f(pl[HW+p])   + b2f(pl[3*HW+p]));
  float acc[32];
#pragma unroll
  for (int j = 0; j < 32; j++) acc[j] = bp[j];
#pragma unroll
  for (int c = 0; c < 32; c++) {
    float vc = (b2f(pao[c*HW+p]) + b2f(pao[(32+c)*HW+p])) * (c < 16 ? inv0 : inv1);
#pragma unroll
    for (int j = 0; j < 32; j++) acc[j] += vc * wp[c*32+j];     // uniform -> s_load
  }
  if (oc == 0) {
#pragma unroll
    for (int j = 0; j < 32; j++) acc[j] += x[j*HW+p];
  } else {
#pragma unroll
    for (int j = 0; j < 32; j++) acc[j] += t4[j*HW+p]*as_[j] + bbs_[j];
  }
  float s = 0.f;
#pragma unroll
  for (int j = 0; j < 32; j++) s += acc[j];
  float m = s * 0.03125f;
  float ss = 0.f;
#pragma unroll
  for (int j = 0; j < 32; j++) { float d = acc[j]-m; ss += d*d; }
  float rs = rsqrtf(ss*0.03125f + 1e-5f);
  float r[32];
#pragma unroll
  for (int j = 0; j < 32; j++) r[j] = mb2[j];
#pragma unroll 1
  for (int half = 0; half < 2; half++) {
    float h[32];
#pragma unroll
    for (int k = 0; k < 32; k++) h[k] = mb1[half*32 + k];
#pragma unroll
    for (int c = 0; c < 32; c++) {
      float ln = (acc[c] - m) * rs * n2g[c] + n2b[c];
#pragma unroll
      for (int k = 0; k < 32; k++) h[k] += ln * mw1[c*64 + half*32 + k];  // s_load
    }
#pragma unroll
    for (int k = 0; k < 32; k++) {
      float xx = h[k];
      float u = 0.7978845608f * (xx + 0.044715f*xx*xx*xx);
      float th = 1.f - 2.f/(1.f + __expf(2.f*u));
      h[k] = 0.5f * xx * (1.f + th);
    }
#pragma unroll
    for (int k = 0; k < 32; k++) {
      float hk = h[k];
#pragma unroll
      for (int j = 0; j < 32; j++) r[j] += hk * mw2[(half*32 + k)*32 + j]; // s_load
    }
  }
#pragma unroll
  for (int j = 0; j < 32; j++) dst[j*HW + p] = acc[j] + r[j];
}

// ---------------- final: out = o1 + o2 + x (o1 aliases out) ----------------
__global__ __launch_bounds__(256) void k_final(
    const float* o1, const float* __restrict__ o2,
    const float* __restrict__ x, float* out) {
  int i = blockIdx.x*256 + threadIdx.x;
  float4 a = ((const float4*)o1)[i];
  float4 b = ((const float4*)o2)[i];
  float4 c = ((const float4*)x)[i];
  float4 r;
  r.x = a.x + b.x + c.x; r.y = a.y + b.y + c.y;
  r.z = a.z + b.z + c.z; r.w = a.w + b.w + c.w;
  ((float4*)out)[i] = r;
}

extern "C" void kernel_launch(void* const* d_in, const int* in_sizes, int n_in,
                              void* d_out, int out_size, void* d_ws, size_t ws_size,
                              hipStream_t stream) {
  const float* x    = (const float*)d_in[0];
  const float* depth= (const float*)d_in[1];
  const int*   rpi  = (const int*)d_in[2];
  const float* cw1  = (const float*)d_in[3],  *cb1 = (const float*)d_in[4];
  const float* cw2  = (const float*)d_in[5],  *cb2 = (const float*)d_in[6];
  const float* cw3  = (const float*)d_in[7],  *cb3 = (const float*)d_in[8];
  const float* cw4  = (const float*)d_in[9],  *cb4 = (const float*)d_in[10];
  const float* in_g = (const float*)d_in[11], *in_b = (const float*)d_in[12];
  const float* n1g  = (const float*)d_in[13], *n1b = (const float*)d_in[14];
  const float* wq   = (const float*)d_in[15], *bq  = (const float*)d_in[16];
  const float* wkv  = (const float*)d_in[17], *bkv = (const float*)d_in[18];
  const float* rpb  = (const float*)d_in[19];
  const float* wp   = (const float*)d_in[20], *bp  = (const float*)d_in[21];
  const float* n2g  = (const float*)d_in[22], *n2b = (const float*)d_in[23];
  const float* mw1  = (const float*)d_in[24], *mb1 = (const float*)d_in[25];
  const float* mw2  = (const float*)d_in[26], *mb2 = (const float*)d_in[27];

  float* W   = (float*)d_ws;
  float* o1  = (float*)d_out;

  // workspace layout (floats) -- total 19284992 floats = 77.14MB (< proven 85.1MB)
  float* t4    = W;                    // 2M
  float* q1    = W + 2097152;          // 2M (o2 aliases after attn)
  float* q2    = W + 4194304;          // 2M (t3 aliases first 1M)
  float* kv1   = W + 6291456;          // 4M
  float* kv2   = W + 10485760;         // 4M
  unsigned short* pao1 = (unsigned short*)(W + 14680064);  // 4M ushorts (t2 aliases first 1M floats)
  unsigned short* pao2 = (unsigned short*)(W + 16777216);  // 4M ushorts
  unsigned short* pl1  = (unsigned short*)(W + 18874368);  // 256K ushorts
  unsigned short* pl2  = (unsigned short*)(W + 19005440);  // 256K ushorts
  unsigned int* biasPk = (unsigned int*)(W + 19136512);    // 147456 words
  float* part  = W + 19283968;         // 1024
  float* t2 = (float*)pao1;
  float* t3 = q2;
  float* o2 = q1;                      // q1 dead after attn; projmlp/final use as o2

  // flat misc: stem(256) + biasPk(576) + lnmm48 roles 0,1 (q1, kv2) = 1344 blocks
  k_misc   <<<1344, 256, 0, stream>>>(depth, cw1, cb1, cw2, cb2, t2,
                                      rpi, rpb, biasPk,
                                      x, t4, part, in_g, in_b, n1g, n1b,
                                      wq, bq, wkv, bkv, q1, kv1, q2, kv2);
  k_conv3  <<<dim3(256,4), 256, 0, stream>>>(t2, cw3, cb3, t3);
  k_conv4  <<<dim3(256,4), 256, 0, stream>>>(t3, cw4, cb4, t4);
  k_instats1<<<512, 256, 0, stream>>>(t4, part);
  // roles 2,3: src=IN(t4) -> q2, kv1
  k_lnmmB2 <<<dim3(256,2), 256, 0, stream>>>(x, t4, part, in_g, in_b, n1g, n1b,
                                             wq, bq, wkv, bkv, q1, kv1, q2, kv2);
  k_attn   <<<dim3(512,4), 256, 0, stream>>>(q1, kv1, pao1, pl1,
                                             q2, kv2, pao2, pl2, biasPk);
  k_projmlp<<<dim3(256,2), 256, 0, stream>>>(pao1, pl1, pao2, pl2, x, t4, part,
                                             in_g, in_b, wp, bp, n2g, n2b,
                                             mw1, mb1, mw2, mb2, o1, o2);
  k_final  <<<2048, 256, 0, stream>>>(o1, o2, x, o1);
}

// Round 2
// 497.961 us; speedup vs baseline: 1.2446x; 1.2446x over previous
//
#include <hip/hip_runtime.h>
#include <hip/hip_bf16.h>

#define HW 65536
#define KHALF 288        // keys per block (split-K half)
#define KPAD2 328        // Vt row stride in shorts: 164 words, 164%32=4 -> 2-way max (free)

typedef __attribute__((ext_vector_type(8))) short bf8;
typedef __attribute__((ext_vector_type(4))) float f4;

__device__ __forceinline__ unsigned short f2b(float x) {   // RNE float->bf16
  unsigned int u = __float_as_uint(x);
  unsigned int r = (u + 0x7fff + ((u >> 16) & 1)) >> 16;
  return (unsigned short)r;
}
__device__ __forceinline__ unsigned int pk2(float lo, float hi) {  // trunc pack 2xbf16
  return (__float_as_uint(hi) & 0xffff0000u) | (__float_as_uint(lo) >> 16);
}
__device__ __forceinline__ unsigned int pkrne(float lo, float hi) { // RNE pack 2xbf16
  return ((unsigned int)f2b(hi) << 16) | (unsigned int)f2b(lo);
}
__device__ __forceinline__ float b2f(unsigned short u) {
  return __uint_as_float(((unsigned int)u) << 16);
}
__device__ __forceinline__ float ex2(float x) { return __builtin_amdgcn_exp2f(x); }

// ================= device bodies =================
__device__ __forceinline__ void stem_front_body(
    int bx, int t, const float* __restrict__ depth,
    const float* __restrict__ cw1, const float* __restrict__ cb1,
    const float* __restrict__ cw2, const float* __restrict__ cb2,
    float* __restrict__ t2) {
  int p = bx * 256 + t;
  int y = p >> 8, x = p & 255;
  float in9[9];
#pragma unroll
  for (int ky = 0; ky < 3; ky++)
#pragma unroll
    for (int kx = 0; kx < 3; kx++) {
      int yy = y + ky - 1, xx = x + kx - 1;
      bool ok = ((unsigned)yy < 256u) && ((unsigned)xx < 256u);
      in9[ky*3+kx] = ok ? depth[yy*256+xx] : 0.f;
    }
  float t1[8];
#pragma unroll
  for (int o = 0; o < 8; o++) {
    float s = cb1[o];
#pragma unroll
    for (int i = 0; i < 9; i++) s += in9[i] * cw1[o*9+i];
    t1[o] = fmaxf(s, 0.f);
  }
#pragma unroll
  for (int o = 0; o < 16; o++) {
    float s = cb2[o];
#pragma unroll
    for (int ci = 0; ci < 8; ci++) s += t1[ci] * cw2[o*8+ci];
    t2[o*HW + p] = fmaxf(s, 0.f);
  }
}

// packed bf16 bias: word W(hd,qt,kt2g,quad,q,r) = pack(bias(key+16,q), bias(key,q))
// with key = kt2g*32 + quad*4 + r ; scale 1/ln2, NO -8 shift (cancels in softmax)
__device__ __forceinline__ void bias_pk_body(
    int bx, int t, const int* __restrict__ rpi,
    const float* __restrict__ rpb, unsigned int* __restrict__ biasPk) {
  int idx = bx*256 + t;        // 576*256 = 147456 exact
  int hd = idx / 73728;
  int rem = idx - hd*73728;
  int qt = rem / 4608;
  int r2 = rem - qt*4608;
  int kt2 = r2 >> 8;
  int w8 = r2 & 255;
  int quad = w8 >> 6, q = (w8 >> 2) & 15, r = w8 & 3;
  int klo = kt2*32 + quad*4 + r;
  int qq = qt*16 + q;
  float lo = rpb[rpi[qq*576 + klo]*2 + hd] * 1.44269504f;
  float hi = rpb[rpi[qq*576 + klo + 16]*2 + hd] * 1.44269504f;
  biasPk[idx] = ((unsigned int)f2b(hi) << 16) | (unsigned int)f2b(lo);
}

// 48-output LN(+IN) matmul slab, weights via uniform (s_load) global reads.
// Outputs PACKED bf16 (2 channels per word). q pre-scaled by 0.25/ln2.
// role 0: src=x      slice0 -> q1 words[0:16) + kv2 words[0:8)
// role 1: src=x      slice1 -> kv2 words[8:32)
// role 2: src=IN(t4) slice0 -> q2 words[0:16) + kv1 words[0:8)
// role 3: src=IN(t4) slice1 -> kv1 words[8:32)
__device__ __forceinline__ void lnmm48_body(
    int role, int bx, int t, float* as_, float* bbs_,
    const float* __restrict__ x, const float* __restrict__ t4,
    const float* __restrict__ part,
    const float* __restrict__ ig, const float* __restrict__ ib,
    const float* __restrict__ n1g, const float* __restrict__ n1b,
    const float* __restrict__ wq, const float* __restrict__ bq,
    const float* __restrict__ wkv, const float* __restrict__ bkv,
    unsigned int* __restrict__ q1, unsigned int* __restrict__ kv1,
    unsigned int* __restrict__ q2, unsigned int* __restrict__ kv2) {
  const float QS = 0.360673503f;   // 0.25/ln2
  bool ain = role >= 2;
  int slice = role & 1;
  const float* src = ain ? t4 : x;
  unsigned int* dq  = ain ? q2 : q1;
  unsigned int* dkv = ain ? kv1 : kv2;
  if (ain) {
    if (t < 32) {
      float s = 0.f, ss = 0.f;
#pragma unroll
      for (int k = 0; k < 16; k++) { s += part[t*16+k]; ss += part[512 + t*16+k]; }
      float m = s * (1.f/65536.f);
      float var = ss * (1.f/65536.f) - m*m;
      float a = rsqrtf(var + 1e-5f) * ig[t];
      as_[t] = a; bbs_[t] = ib[t] - m*a;
    }
    __syncthreads();
  }
  int p = bx*256 + t;
  float v[32]; float s = 0.f;
  if (ain) {
#pragma unroll
    for (int c = 0; c < 32; c++) { v[c] = src[c*HW+p]*as_[c] + bbs_[c]; s += v[c]; }
  } else {
#pragma unroll
    for (int c = 0; c < 32; c++) { v[c] = src[c*HW+p]; s += v[c]; }
  }
  float m = s * 0.03125f;
  float ss = 0.f;
#pragma unroll
  for (int c = 0; c < 32; c++) { float d = v[c]-m; ss += d*d; }
  float rs = rsqrtf(ss*0.03125f + 1e-5f);
  float acc[48];
  if (slice == 0) {
#pragma unroll
    for (int j = 0; j < 32; j++) acc[j] = bq[j];
#pragma unroll
    for (int j = 0; j < 16; j++) acc[32+j] = bkv[j];
#pragma unroll
    for (int c = 0; c < 32; c++) {
      float ln = (v[c]-m)*rs*n1g[c] + n1b[c];
#pragma unroll
      for (int j = 0; j < 32; j++) acc[j] += ln*wq[c*32+j];      // uniform -> s_load
#pragma unroll
      for (int j = 0; j < 16; j++) acc[32+j] += ln*wkv[c*64+j];  // uniform -> s_load
    }
#pragma unroll
    for (int j2 = 0; j2 < 16; j2++)
      dq[j2*HW+p] = pkrne(acc[2*j2]*QS, acc[2*j2+1]*QS);
#pragma unroll
    for (int c2 = 0; c2 < 8; c2++)
      dkv[c2*HW+p] = pkrne(acc[32+2*c2], acc[32+2*c2+1]);
  } else {
#pragma unroll
    for (int j = 0; j < 48; j++) acc[j] = bkv[16+j];
#pragma unroll
    for (int c = 0; c < 32; c++) {
      float ln = (v[c]-m)*rs*n1g[c] + n1b[c];
#pragma unroll
      for (int j = 0; j < 48; j++) acc[j] += ln*wkv[c*64+16+j];  // uniform -> s_load
    }
#pragma unroll
    for (int c2 = 0; c2 < 24; c2++)
      dkv[(8+c2)*HW+p] = pkrne(acc[2*c2], acc[2*c2+1]);
  }
}

// ================= kernels =================
// flat mega-launch: [0,256) stem | [256,832) biasPk | [832,1344) lnmm48 roles 0,1
__global__ __launch_bounds__(256, 2) void k_misc(
    const float* __restrict__ depth,
    const float* __restrict__ cw1, const float* __restrict__ cb1,
    const float* __restrict__ cw2, const float* __restrict__ cb2,
    float* __restrict__ t2,
    const int* __restrict__ rpi, const float* __restrict__ rpb,
    unsigned int* __restrict__ biasPk,
    const float* __restrict__ x, const float* __restrict__ t4,
    const float* __restrict__ part,
    const float* __restrict__ ig, const float* __restrict__ ib,
    const float* __restrict__ n1g, const float* __restrict__ n1b,
    const float* __restrict__ wq, const float* __restrict__ bq,
    const float* __restrict__ wkv, const float* __restrict__ bkv,
    unsigned int* q1, unsigned int* kv1, unsigned int* q2, unsigned int* kv2) {
  __shared__ float as_[32], bbs_[32];
  int id = blockIdx.x, t = threadIdx.x;
  if (id < 256) { stem_front_body(id, t, depth, cw1, cb1, cw2, cb2, t2); return; }
  if (id < 832) { bias_pk_body(id - 256, t, rpi, rpb, biasPk); return; }
  int r = id - 832;
  lnmm48_body(r >> 8, r & 255, t, as_, bbs_,
              x, t4, part, ig, ib, n1g, n1b, wq, bq, wkv, bkv, q1, kv1, q2, kv2);
}

__global__ __launch_bounds__(256, 2) void k_lnmmB2(
    const float* __restrict__ x, const float* __restrict__ t4,
    const float* __restrict__ part,
    const float* __restrict__ ig, const float* __restrict__ ib,
    const float* __restrict__ n1g, const float* __restrict__ n1b,
    const float* __restrict__ wq, const float* __restrict__ bq,
    const float* __restrict__ wkv, const float* __restrict__ bkv,
    unsigned int* q1, unsigned int* kv1, unsigned int* q2, unsigned int* kv2) {
  __shared__ float as_[32], bbs_[32];
  lnmm48_body(2 + blockIdx.y, blockIdx.x, threadIdx.x, as_, bbs_,
              x, t4, part, ig, ib, n1g, n1b, wq, bq, wkv, bkv, q1, kv1, q2, kv2);
}

__global__ __launch_bounds__(256) void k_conv3(
    const float* __restrict__ t2, const float* __restrict__ cw3,
    const float* __restrict__ cb3, float* __restrict__ t3) {
  int t = threadIdx.x;
  int p = blockIdx.x*256 + t;
  int og = blockIdx.y;
  int y = p >> 8, x = p & 255;
  float acc[4];
#pragma unroll
  for (int o = 0; o < 4; o++) acc[o] = cb3[og*4+o];
#pragma unroll 1
  for (int tap = 0; tap < 9; tap++) {
    int ky = tap/3 - 1, kx = tap - (tap/3)*3 - 1;
    int yy = y+ky, xx = x+kx;
    bool ok = ((unsigned)yy < 256u) && ((unsigned)xx < 256u);
    int pp = yy*256+xx;
#pragma unroll
    for (int ci = 0; ci < 16; ci++) {
      float v = ok ? t2[ci*HW+pp] : 0.f;
#pragma unroll
      for (int o = 0; o < 4; o++)
        acc[o] += v * cw3[(og*4+o)*144 + ci*9 + tap];   // uniform -> s_load
    }
  }
#pragma unroll
  for (int o = 0; o < 4; o++) t3[(og*4+o)*HW+p] = fmaxf(acc[o], 0.f);
}

__global__ __launch_bounds__(256) void k_conv4(
    const float* __restrict__ t3, const float* __restrict__ cw4,
    const float* __restrict__ cb4, float* __restrict__ t4) {
  int t = threadIdx.x;
  int p = blockIdx.x*256 + t;
  int og = blockIdx.y;           // 8 outputs per group
  float v[16];
#pragma unroll
  for (int ci = 0; ci < 16; ci++) v[ci] = t3[ci*HW+p];
#pragma unroll
  for (int o = 0; o < 8; o++) {
    int oo = og*8 + o;
    float s = cb4[oo];
#pragma unroll
    for (int ci = 0; ci < 16; ci++) s += v[ci]*cw4[oo*16+ci];
    t4[oo*HW+p] = s;
  }
}

__global__ __launch_bounds__(256) void k_instats1(const float* __restrict__ t4,
                                                  float* __restrict__ part) {
  int c = blockIdx.x >> 4, seg = blockIdx.x & 15;   // 512 blocks
  const float4* src = (const float4*)(t4 + c*HW + seg*4096);
  float s = 0.f, ss = 0.f;
  for (int i = threadIdx.x; i < 1024; i += 256) {
    float4 v = src[i];
    s  += v.x + v.y + v.z + v.w;
    ss += v.x*v.x + v.y*v.y + v.z*v.z + v.w*v.w;
  }
#pragma unroll
  for (int off = 32; off > 0; off >>= 1) {
    s  += __shfl_down(s, off, 64);
    ss += __shfl_down(ss, off, 64);
  }
  __shared__ float sh[8];
  int wid = threadIdx.x >> 6;
  if ((threadIdx.x & 63) == 0) { sh[wid] = s; sh[4+wid] = ss; }
  __syncthreads();
  if (threadIdx.x == 0) {
    part[blockIdx.x]       = sh[0]+sh[1]+sh[2]+sh[3];
    part[512 + blockIdx.x] = sh[4]+sh[5]+sh[6]+sh[7];
  }
}

// ---------------- MFMA attention: split-K (288 keys/block), bf16-packed q/kv ----------------
// y: sel = y>>1 (ocab), half = y&1 (key half). Partial o (bf16) + partial l (bf16) out.
// launch_bounds(256,4): safe VGPR budget (128); if alloc lands <=64, HW gives 8 blocks/CU.
__global__ __launch_bounds__(256, 4) void k_attn(
    const unsigned int* __restrict__ qA, const unsigned int* __restrict__ kvA,
    unsigned short* __restrict__ paoA, unsigned short* __restrict__ plA,
    const unsigned int* __restrict__ qB, const unsigned int* __restrict__ kvB,
    unsigned short* __restrict__ paoB, unsigned short* __restrict__ plB,
    const unsigned int* __restrict__ biasPk) {
  __shared__ __align__(16) unsigned short Ks[KHALF*16];   // [key][d]  9216B
  __shared__ __align__(16) unsigned short Vt[16*KPAD2];   // [d][key-permuted] 10496B

  int sel = blockIdx.y >> 1, half = blockIdx.y & 1;
  const unsigned int* q  = sel ? qB  : qA;
  const unsigned int* kv = sel ? kvB : kvA;
  unsigned short* pao = sel ? paoB : paoA;
  unsigned short* pl  = sel ? plB  : plA;

  // XCD swizzle: contiguous window stripes per XCD for kv-overlap L2 reuse
  int id = blockIdx.x;                       // 0..511
  int lin = ((id & 7) << 6) | (id >> 3);
  int wi = lin >> 1, hd = lin & 1;
  int wy = wi >> 4, wx = wi & 15;
  int t = threadIdx.x;
  int by = wy*16 - 4 + half*12, bx = wx*16 - 4;
  int krow = hd*8, vrow = 16 + hd*8;         // packed word-row bases

  int wave = t >> 6, lane = t & 63;
  int quad = lane >> 4, l16 = lane & 15;
  const bf8 zero8 = {0,0,0,0,0,0,0,0};

  // --- Q fragments: 4 packed dword loads each (pre-scaled bf16 in memory)
  bf8 qf[4];
#pragma unroll
  for (int qi = 0; qi < 4; qi++) {
    if (quad < 2) {
      int qt = wave*4 + qi;
      int prow = (wy*16 + qt)*256 + wx*16 + l16;
      union { unsigned int u[4]; bf8 v; } Q;
#pragma unroll
      for (int jw = 0; jw < 4; jw++)
        Q.u[jw] = q[(krow + quad*4 + jw)*HW + prow];
      qf[qi] = Q.v;
    } else {
      qf[qi] = zero8;
    }
  }

  // --- stage K (row-major) and V (transposed, slot-permuted), 288 keys = 12 rows of 24
  for (int e = t; e < KHALF; e += 256) {
    int dy = e / 24, dx = e - dy*24;
    int yy = by + dy, xx = bx + dx;
    bool ok = ((unsigned)yy < 256u) && ((unsigned)xx < 256u);
    int pp = yy*256 + xx;
    int off = e & 31;
    int ppos = ((off & 12) << 1) + ((off >> 4) << 2) + (off & 3);
    int vcol = (e & ~31) + ppos;
    unsigned int kwd[8], vwd[8];
#pragma unroll
    for (int i = 0; i < 8; i++) {
      kwd[i] = ok ? kv[(krow + i)*HW + pp] : 0u;
      vwd[i] = ok ? kv[(vrow + i)*HW + pp] : 0u;
    }
    *(uint4*)&Ks[e*16]     = *(const uint4*)&kwd[0];
    *(uint4*)&Ks[e*16 + 8] = *(const uint4*)&kwd[4];
#pragma unroll
    for (int d = 0; d < 16; d++)
      Vt[d*KPAD2 + vcol] = (unsigned short)(vwd[d >> 1] >> ((d & 1)*16));
  }
  __syncthreads();

  f4 oacc[4];
  float lr[4];
#pragma unroll
  for (int qi = 0; qi < 4; qi++) {
    oacc[qi] = (f4){0.f,0.f,0.f,0.f};
    lr[qi] = 0.f;
  }
  unsigned int bb0 = (unsigned)((hd*16 + wave*4)*4608 + half*2304 + quad*64 + l16*4);

#pragma unroll 2
  for (int kt2 = 0; kt2 < 9; kt2++) {
    int k0 = kt2 * 32;
    bf8 kf0 = zero8, kf1 = zero8;
    if (quad < 2) {
      kf0 = *(const bf8*)&Ks[(k0 + l16)*16 + quad*8];
      kf1 = *(const bf8*)&Ks[(k0 + 16 + l16)*16 + quad*8];
    }
    bf8 vf = *(const bf8*)&Vt[l16*KPAD2 + k0 + quad*8];
    __builtin_amdgcn_s_setprio(1);
#pragma unroll
    for (int qi = 0; qi < 4; qi++) {
      union { uint4 v; unsigned int u[4]; } bw;
      bw.v = *(const uint4*)&biasPk[bb0 + qi*4608 + kt2*256];
      f4 b0, b1;
#pragma unroll
      for (int r = 0; r < 4; r++) {
        unsigned int u = bw.u[r];
        b0[r] = __uint_as_float(u << 16);
        b1[r] = __uint_as_float(u & 0xffff0000u);
      }
      f4 s0 = __builtin_amdgcn_mfma_f32_16x16x32_bf16(kf0, qf[qi], b0, 0, 0, 0);
      f4 s1 = __builtin_amdgcn_mfma_f32_16x16x32_bf16(kf1, qf[qi], b1, 0, 0, 0);
      float p0[4], p1[4];
#pragma unroll
      for (int r = 0; r < 4; r++) {
        p0[r] = ex2(s0[r]);
        p1[r] = ex2(s1[r]);
        lr[qi] += p0[r] + p1[r];
      }
      union { unsigned int u[4]; bf8 v; } P;
      P.u[0] = pk2(p0[0], p0[1]); P.u[1] = pk2(p0[2], p0[3]);
      P.u[2] = pk2(p1[0], p1[1]); P.u[3] = pk2(p1[2], p1[3]);
      oacc[qi] = __builtin_amdgcn_mfma_f32_16x16x32_bf16(P.v, vf, oacc[qi], 0, 0, 0);
    }
    __builtin_amdgcn_s_setprio(0);
  }
#pragma unroll
  for (int qi = 0; qi < 4; qi++) {
    lr[qi] += __shfl_xor(lr[qi], 16, 64);
    lr[qi] += __shfl_xor(lr[qi], 32, 64);
  }
#pragma unroll
  for (int qi = 0; qi < 4; qi++) {
    int qt = wave*4 + qi;
#pragma unroll
    for (int r = 0; r < 4; r++) {
      int col = quad*4 + r;
      pao[(half*32 + hd*16 + l16)*HW + (wy*16 + qt)*256 + wx*16 + col] = f2b(oacc[qi][r]);
    }
    if (quad == 0) {
      pl[(half*2 + hd)*HW + (wy*16 + qt)*256 + wx*16 + l16] = f2b(lr[qi]);
    }
  }
}

// ---------------- merge partials + proj + shortcut + LN + MLP (s_load weights) ----------------
__global__ __launch_bounds__(256) void k_projmlp(
    const unsigned short* __restrict__ pao1, const unsigned short* __restrict__ pl1,
    const unsigned short* __restrict__ pao2, const unsigned short* __restrict__ pl2,
    const float* __restrict__ x, const float* __restrict__ t4,
    const float* __restrict__ part,
    const float* __restrict__ ig, const float* __restrict__ ib,
    const float* __restrict__ wp, const float* __restrict__ bp,
    const float* __restrict__ n2g, const float* __restrict__ n2b,
    const float* __restrict__ mw1, const float* __restrict__ mb1,
    const float* __restrict__ mw2, const float* __restrict__ mb2,
    float* __restrict__ o1, float* __restrict__ o2) {
  int oc = blockIdx.y;
  const unsigned short* pao = oc ? pao2 : pao1;
  const unsigned short* pl  = oc ? pl2  : pl1;
  float* dst = oc ? o2 : o1;
  __shared__ float as_[32], bbs_[32];
  int t = threadIdx.x;
  if (t < 32) {
    float s = 0.f, ss = 0.f;
#pragma unroll
    for (int k = 0; k < 16; k++) { s += part[t*16+k]; ss += part[512 + t*16+k]; }
    float m = s * (1.f/65536.f);
    float var = ss * (1.f/65536.f) - m*m;
    float a = rsqrtf(var + 1e-5f) * ig[t];
    as_[t] = a; bbs_[t] = ib[t] - m*a;
  }
  __syncthreads();
  int p = blockIdx.x*256 + t;
  // merge split-K halves: o = (oA + oB) / (lA + lB), per head
  float inv0 = 1.f / (b2f(pl[p])      + b2f(pl[2*HW+p]));
  float inv1 = 1.f / (b2f(pl[HW+p])   + b2f(pl[3*HW+p]));
  float acc[32];
#pragma unroll
  for (int j = 0; j < 32; j++) acc[j] = bp[j];
#pragma unroll
  for (int c = 0; c < 32; c++) {
    float vc = (b2f(pao[c*HW+p]) + b2f(pao[(32+c)*HW+p])) * (c < 16 ? inv0 : inv1);
#pragma unroll
    for (int j = 0; j < 32; j++) acc[j] += vc * wp[c*32+j];     // uniform -> s_load
  }
  if (oc == 0) {
#pragma unroll
    for (int j = 0; j < 32; j++) acc[j] += x[j*HW+p];
  } else {
#pragma unroll
    for (int j = 0; j < 32; j++) acc[j] += t4[j*HW+p]*as_[j] + bbs_[j];
  }
  float s = 0.f;
#pragma unroll
  for (int j = 0; j < 32; j++) s += acc[j];
  float m = s * 0.03125f;
  float ss = 0.f;
#pragma unroll
  for (int j = 0; j < 32; j++) { float d = acc[j]-m; ss += d*d; }
  float rs = rsqrtf(ss*0.03125f + 1e-5f);
  float r[32];
#pragma unroll
  for (int j = 0; j < 32; j++) r[j] = mb2[j];
#pragma unroll 1
  for (int half = 0; half < 2; half++) {
    float h[32];
#pragma unroll
    for (int k = 0; k < 32; k++) h[k] = mb1[half*32 + k];
#pragma unroll
    for (int c = 0; c < 32; c++) {
      float ln = (acc[c] - m) * rs * n2g[c] + n2b[c];
#pragma unroll
      for (int k = 0; k < 32; k++) h[k] += ln * mw1[c*64 + half*32 + k];  // s_load
    }
#pragma unroll
    for (int k = 0; k < 32; k++) {
      float xx = h[k];
      float u = 0.7978845608f * (xx + 0.044715f*xx*xx*xx);
      float th = 1.f - 2.f/(1.f + __expf(2.f*u));
      h[k] = 0.5f * xx * (1.f + th);
    }
#pragma unroll
    for (int k = 0; k < 32; k++) {
      float hk = h[k];
#pragma unroll
      for (int j = 0; j < 32; j++) r[j] += hk * mw2[(half*32 + k)*32 + j]; // s_load
    }
  }
#pragma unroll
  for (int j = 0; j < 32; j++) dst[j*HW + p] = acc[j] + r[j];
}

// ---------------- final: out = o1 + o2 + x (o1 aliases out) ----------------
__global__ __launch_bounds__(256) void k_final(
    const float* o1, const float* __restrict__ o2,
    const float* __restrict__ x, float* out) {
  int i = blockIdx.x*256 + threadIdx.x;
  float4 a = ((const float4*)o1)[i];
  float4 b = ((const float4*)o2)[i];
  float4 c = ((const float4*)x)[i];
  float4 r;
  r.x = a.x + b.x + c.x; r.y = a.y + b.y + c.y;
  r.z = a.z + b.z + c.z; r.w = a.w + b.w + c.w;
  ((float4*)out)[i] = r;
}

extern "C" void kernel_launch(void* const* d_in, const int* in_sizes, int n_in,
                              void* d_out, int out_size, void* d_ws, size_t ws_size,
                              hipStream_t stream) {
  const float* x    = (const float*)d_in[0];
  const float* depth= (const float*)d_in[1];
  const int*   rpi  = (const int*)d_in[2];
  const float* cw1  = (const float*)d_in[3],  *cb1 = (const float*)d_in[4];
  const float* cw2  = (const float*)d_in[5],  *cb2 = (const float*)d_in[6];
  const float* cw3  = (const float*)d_in[7],  *cb3 = (const float*)d_in[8];
  const float* cw4  = (const float*)d_in[9],  *cb4 = (const float*)d_in[10];
  const float* in_g = (const float*)d_in[11], *in_b = (const float*)d_in[12];
  const float* n1g  = (const float*)d_in[13], *n1b = (const float*)d_in[14];
  const float* wq   = (const float*)d_in[15], *bq  = (const float*)d_in[16];
  const float* wkv  = (const float*)d_in[17], *bkv = (const float*)d_in[18];
  const float* rpb  = (const float*)d_in[19];
  const float* wp   = (const float*)d_in[20], *bp  = (const float*)d_in[21];
  const float* n2g  = (const float*)d_in[22], *n2b = (const float*)d_in[23];
  const float* mw1  = (const float*)d_in[24], *mb1 = (const float*)d_in[25];
  const float* mw2  = (const float*)d_in[26], *mb2 = (const float*)d_in[27];

  float* W   = (float*)d_ws;
  float* o1  = (float*)d_out;

  // workspace layout (floats) -- same slots as before, q/kv now packed bf16 (half-used)
  float* t4    = W;                    // 2M
  float* q1f   = W + 2097152;          // 2M slot; q1 packed uses 1M words (o2 aliases)
  float* q2f   = W + 4194304;          // 2M slot (t3 aliases first 1M floats)
  float* kv1f  = W + 6291456;          // 4M slot; packed uses 2M words
  float* kv2f  = W + 10485760;         // 4M slot
  unsigned short* pao1 = (unsigned short*)(W + 14680064);  // 4M ushorts (t2 aliases first 1M floats)
  unsigned short* pao2 = (unsigned short*)(W + 16777216);  // 4M ushorts
  unsigned short* pl1  = (unsigned short*)(W + 18874368);  // 256K ushorts
  unsigned short* pl2  = (unsigned short*)(W + 19005440);  // 256K ushorts
  unsigned int* biasPk = (unsigned int*)(W + 19136512);    // 147456 words
  float* part  = W + 19283968;         // 1024
  float* t2 = (float*)pao1;
  float* t3 = q2f;
  float* o2 = q1f;                     // q1 dead after attn; projmlp/final use as o2
  unsigned int* q1  = (unsigned int*)q1f;
  unsigned int* q2  = (unsigned int*)q2f;
  unsigned int* kv1 = (unsigned int*)kv1f;
  unsigned int* kv2 = (unsigned int*)kv2f;

  // flat misc: stem(256) + biasPk(576) + lnmm48 roles 0,1 (q1, kv2) = 1344 blocks
  k_misc   <<<1344, 256, 0, stream>>>(depth, cw1, cb1, cw2, cb2, t2,
                                      rpi, rpb, biasPk,
                                      x, t4, part, in_g, in_b, n1g, n1b,
                                      wq, bq, wkv, bkv, q1, kv1, q2, kv2);
  k_conv3  <<<dim3(256,4), 256, 0, stream>>>(t2, cw3, cb3, t3);
  k_conv4  <<<dim3(256,4), 256, 0, stream>>>(t3, cw4, cb4, t4);
  k_instats1<<<512, 256, 0, stream>>>(t4, part);
  // roles 2,3: src=IN(t4) -> q2, kv1
  k_lnmmB2 <<<dim3(256,2), 256, 0, stream>>>(x, t4, part, in_g, in_b, n1g, n1b,
                                             wq, bq, wkv, bkv, q1, kv1, q2, kv2);
  k_attn   <<<dim3(512,4), 256, 0, stream>>>(q1, kv1, pao1, pl1,
                                             q2, kv2, pao2, pl2, biasPk);
  k_projmlp<<<dim3(256,2), 256, 0, stream>>>(pao1, pl1, pao2, pl2, x, t4, part,
                                             in_g, in_b, wp, bp, n2g, n2b,
                                             mw1, mb1, mw2, mb2, o1, o2);
  k_final  <<<2048, 256, 0, stream>>>(o1, o2, x, o1);
}

// Round 3
// 256.038 us; speedup vs baseline: 2.4205x; 1.9449x over previous
//
#include <hip/hip_runtime.h>
#include <hip/hip_bf16.h>

#define HW 65536
#define KPAD 584   // Vt row stride (bf16): 1168B rows, 16B-aligned

typedef __attribute__((ext_vector_type(8))) short bf8;
typedef __attribute__((ext_vector_type(4))) float f4;

__device__ __forceinline__ unsigned short f2b(float x) {   // RNE float->bf16
  unsigned int u = __float_as_uint(x);
  unsigned int r = (u + 0x7fff + ((u >> 16) & 1)) >> 16;
  return (unsigned short)r;
}
__device__ __forceinline__ unsigned int pk2(float lo, float hi) {  // trunc pack 2xbf16
  return (__float_as_uint(hi) & 0xffff0000u) | (__float_as_uint(lo) >> 16);
}
__device__ __forceinline__ unsigned int pkrne(float lo, float hi) { // RNE pack 2xbf16
  return ((unsigned int)f2b(hi) << 16) | (unsigned int)f2b(lo);
}
__device__ __forceinline__ float ex2(float x) { return __builtin_amdgcn_exp2f(x); }

// ================= device bodies =================
__device__ __forceinline__ void stem_front_body(
    int bx, int t, const float* __restrict__ depth,
    const float* __restrict__ cw1, const float* __restrict__ cb1,
    const float* __restrict__ cw2, const float* __restrict__ cb2,
    float* __restrict__ t2) {
  int p = bx * 256 + t;
  int y = p >> 8, x = p & 255;
  float in9[9];
#pragma unroll
  for (int ky = 0; ky < 3; ky++)
#pragma unroll
    for (int kx = 0; kx < 3; kx++) {
      int yy = y + ky - 1, xx = x + kx - 1;
      bool ok = ((unsigned)yy < 256u) && ((unsigned)xx < 256u);
      in9[ky*3+kx] = ok ? depth[yy*256+xx] : 0.f;
    }
  float t1[8];
#pragma unroll
  for (int o = 0; o < 8; o++) {
    float s = cb1[o];
#pragma unroll
    for (int i = 0; i < 9; i++) s += in9[i] * cw1[o*9+i];
    t1[o] = fmaxf(s, 0.f);
  }
#pragma unroll
  for (int o = 0; o < 16; o++) {
    float s = cb2[o];
#pragma unroll
    for (int ci = 0; ci < 8; ci++) s += t1[ci] * cw2[o*8+ci];
    t2[o*HW + p] = fmaxf(s, 0.f);
  }
}

// bias layout per (hd,qt): [kb=key/4][q16][r=key&3]; pre-scaled by 1/ln2 with -8 shift
__device__ __forceinline__ void bias_body(
    int bx, int t, const int* __restrict__ rpi,
    const float* __restrict__ rpb, float* __restrict__ biasT) {
  int idx = bx*256 + t;        // 1152*256 = 294912 exact
  int hd = idx / 147456;
  int rem = idx - hd*147456;
  int qt = rem / 9216;
  int r2 = rem - qt*9216;
  int kb = r2 >> 6;
  int q16 = (r2 >> 2) & 15;
  int r = r2 & 3;
  int key = kb*4 + r;
  int qq = qt*16 + q16;
  biasT[idx] = (rpb[rpi[qq*576 + key]*2 + hd] - 8.0f) * 1.44269504f;
}

// 48-output LN(+IN) matmul slab, LDS-staged weights, PACKED bf16 outputs.
// q pre-scaled by 0.25/ln2 (RNE pack).
// role 0: src=x      slice0 -> q1 words[0:16) + kv2 words[0:8)
// role 1: src=x      slice1 -> kv2 words[8:32)
// role 2: src=IN(t4) slice0 -> q2 words[0:16) + kv1 words[0:8)
// role 3: src=IN(t4) slice1 -> kv1 words[8:32)
__device__ __forceinline__ void lnmm48_body(
    int role, int bx, int t,
    float* ws, float* gs, float* bs, float* b2s, float* as_, float* bbs_,
    const float* __restrict__ x, const float* __restrict__ t4,
    const float* __restrict__ part,
    const float* __restrict__ ig, const float* __restrict__ ib,
    const float* __restrict__ n1g, const float* __restrict__ n1b,
    const float* __restrict__ wq, const float* __restrict__ bq,
    const float* __restrict__ wkv, const float* __restrict__ bkv,
    unsigned int* __restrict__ q1, unsigned int* __restrict__ kv1,
    unsigned int* __restrict__ q2, unsigned int* __restrict__ kv2) {
  const float QS = 0.360673503f;   // 0.25/ln2
  bool ain = role >= 2;
  int slice = role & 1;
  const float* src = ain ? t4 : x;
  unsigned int* dq  = ain ? q2 : q1;
  unsigned int* dkv = ain ? kv1 : kv2;
  // stage weights: ws[c*48 + j]
  for (int i = t; i < 1536; i += 256) {
    int c = i / 48, j = i - c*48;
    ws[i] = slice ? wkv[c*64 + 16 + j]
                  : (j < 32 ? wq[c*32 + j] : wkv[c*64 + (j - 32)]);
  }
  if (t < 48) b2s[t] = slice ? bkv[16 + t] : (t < 32 ? bq[t] : bkv[t - 32]);
  if (t < 32) {
    gs[t] = n1g[t]; bs[t] = n1b[t];
    if (ain) {
      float s = 0.f, ss = 0.f;
#pragma unroll
      for (int k = 0; k < 16; k++) { s += part[t*16+k]; ss += part[512 + t*16+k]; }
      float m = s * (1.f/65536.f);
      float var = ss * (1.f/65536.f) - m*m;
      float a = rsqrtf(var + 1e-5f) * ig[t];
      as_[t] = a; bbs_[t] = ib[t] - m*a;
    }
  }
  __syncthreads();
  int p = bx*256 + t;
  float v[32]; float s = 0.f;
  if (ain) {
#pragma unroll
    for (int c = 0; c < 32; c++) { v[c] = src[c*HW+p]*as_[c] + bbs_[c]; s += v[c]; }
  } else {
#pragma unroll
    for (int c = 0; c < 32; c++) { v[c] = src[c*HW+p]; s += v[c]; }
  }
  float m = s * 0.03125f;
  float ss = 0.f;
#pragma unroll
  for (int c = 0; c < 32; c++) { float d = v[c]-m; ss += d*d; }
  float rs = rsqrtf(ss*0.03125f + 1e-5f);
  float acc[48];
#pragma unroll
  for (int j = 0; j < 48; j++) acc[j] = b2s[j];
#pragma unroll
  for (int c = 0; c < 32; c++) {
    float ln = (v[c]-m)*rs*gs[c] + bs[c];
    const float4* w4 = (const float4*)&ws[c*48];
#pragma unroll
    for (int j4 = 0; j4 < 12; j4++) {
      float4 w = w4[j4];
      acc[j4*4+0] += ln*w.x; acc[j4*4+1] += ln*w.y;
      acc[j4*4+2] += ln*w.z; acc[j4*4+3] += ln*w.w;
    }
  }
  if (slice == 0) {
#pragma unroll
    for (int j2 = 0; j2 < 16; j2++)
      dq[j2*HW+p] = pkrne(acc[2*j2]*QS, acc[2*j2+1]*QS);
#pragma unroll
    for (int c2 = 0; c2 < 8; c2++)
      dkv[c2*HW+p] = pkrne(acc[32+2*c2], acc[32+2*c2+1]);
  } else {
#pragma unroll
    for (int c2 = 0; c2 < 24; c2++)
      dkv[(8+c2)*HW+p] = pkrne(acc[2*c2], acc[2*c2+1]);
  }
}

// ================= kernels =================
// flat mega-launch: [0,256) stem | [256,1408) bias | [1408,1920) lnmm48 roles 0,1
__global__ __launch_bounds__(256) void k_misc(
    const float* __restrict__ depth,
    const float* __restrict__ cw1, const float* __restrict__ cb1,
    const float* __restrict__ cw2, const float* __restrict__ cb2,
    float* __restrict__ t2,
    const int* __restrict__ rpi, const float* __restrict__ rpb, float* __restrict__ biasT,
    const float* __restrict__ x, const float* __restrict__ t4,
    const float* __restrict__ part,
    const float* __restrict__ ig, const float* __restrict__ ib,
    const float* __restrict__ n1g, const float* __restrict__ n1b,
    const float* __restrict__ wq, const float* __restrict__ bq,
    const float* __restrict__ wkv, const float* __restrict__ bkv,
    unsigned int* q1, unsigned int* kv1, unsigned int* q2, unsigned int* kv2) {
  __shared__ __align__(16) float ws[1536];
  __shared__ float gs[32], bs[32], b2s[48], as_[32], bbs_[32];
  int id = blockIdx.x, t = threadIdx.x;
  if (id < 256) { stem_front_body(id, t, depth, cw1, cb1, cw2, cb2, t2); return; }
  if (id < 1408) { bias_body(id - 256, t, rpi, rpb, biasT); return; }
  int r = id - 1408;
  lnmm48_body(r >> 8, r & 255, t, ws, gs, bs, b2s, as_, bbs_,
              x, t4, part, ig, ib, n1g, n1b, wq, bq, wkv, bkv, q1, kv1, q2, kv2);
}

__global__ __launch_bounds__(256) void k_lnmmB(
    const float* __restrict__ x, const float* __restrict__ t4,
    const float* __restrict__ part,
    const float* __restrict__ ig, const float* __restrict__ ib,
    const float* __restrict__ n1g, const float* __restrict__ n1b,
    const float* __restrict__ wq, const float* __restrict__ bq,
    const float* __restrict__ wkv, const float* __restrict__ bkv,
    unsigned int* q1, unsigned int* kv1, unsigned int* q2, unsigned int* kv2) {
  __shared__ __align__(16) float ws[1536];
  __shared__ float gs[32], bs[32], b2s[48], as_[32], bbs_[32];
  lnmm48_body(2 + blockIdx.y, blockIdx.x, threadIdx.x, ws, gs, bs, b2s, as_, bbs_,
              x, t4, part, ig, ib, n1g, n1b, wq, bq, wkv, bkv, q1, kv1, q2, kv2);
}

__global__ __launch_bounds__(256) void k_conv3(
    const float* __restrict__ t2, const float* __restrict__ cw3,
    const float* __restrict__ cb3, float* __restrict__ t3) {
  int t = threadIdx.x;
  int p = blockIdx.x*256 + t;
  int og = blockIdx.y;
  int y = p >> 8, x = p & 255;
  float acc[4];
#pragma unroll
  for (int o = 0; o < 4; o++) acc[o] = cb3[og*4+o];
#pragma unroll 1
  for (int tap = 0; tap < 9; tap++) {
    int ky = tap/3 - 1, kx = tap - (tap/3)*3 - 1;
    int yy = y+ky, xx = x+kx;
    bool ok = ((unsigned)yy < 256u) && ((unsigned)xx < 256u);
    int pp = yy*256+xx;
#pragma unroll
    for (int ci = 0; ci < 16; ci++) {
      float v = ok ? t2[ci*HW+pp] : 0.f;
#pragma unroll
      for (int o = 0; o < 4; o++)
        acc[o] += v * cw3[(og*4+o)*144 + ci*9 + tap];   // uniform -> s_load
    }
  }
#pragma unroll
  for (int o = 0; o < 4; o++) t3[(og*4+o)*HW+p] = fmaxf(acc[o], 0.f);
}

// conv4 split over y: 8 outputs per block -> 1024 blocks
__global__ __launch_bounds__(256) void k_conv4(
    const float* __restrict__ t3, const float* __restrict__ cw4,
    const float* __restrict__ cb4, float* __restrict__ t4) {
  int t = threadIdx.x;
  int p = blockIdx.x*256 + t;
  int og = blockIdx.y;           // 8 outputs per group
  float v[16];
#pragma unroll
  for (int ci = 0; ci < 16; ci++) v[ci] = t3[ci*HW+p];
#pragma unroll
  for (int o = 0; o < 8; o++) {
    int oo = og*8 + o;
    float s = cb4[oo];
#pragma unroll
    for (int ci = 0; ci < 16; ci++) s += v[ci]*cw4[oo*16+ci];
    t4[oo*HW+p] = s;
  }
}

__global__ __launch_bounds__(256) void k_instats1(const float* __restrict__ t4,
                                                  float* __restrict__ part) {
  int c = blockIdx.x >> 4, seg = blockIdx.x & 15;   // 512 blocks
  const float4* src = (const float4*)(t4 + c*HW + seg*4096);
  float s = 0.f, ss = 0.f;
  for (int i = threadIdx.x; i < 1024; i += 256) {
    float4 v = src[i];
    s  += v.x + v.y + v.z + v.w;
    ss += v.x*v.x + v.y*v.y + v.z*v.z + v.w*v.w;
  }
#pragma unroll
  for (int off = 32; off > 0; off >>= 1) {
    s  += __shfl_down(s, off, 64);
    ss += __shfl_down(ss, off, 64);
  }
  __shared__ float sh[8];
  int wid = threadIdx.x >> 6;
  if ((threadIdx.x & 63) == 0) { sh[wid] = s; sh[4+wid] = ss; }
  __syncthreads();
  if (threadIdx.x == 0) {
    part[blockIdx.x]       = sh[0]+sh[1]+sh[2]+sh[3];
    part[512 + blockIdx.x] = sh[4]+sh[5]+sh[6]+sh[7];
  }
}

// ---------------- MFMA attention: round-0 structure, bf16-packed q/kv inputs ----------------
__global__ __launch_bounds__(256, 4) void k_attn(
    const unsigned int* __restrict__ qA, const unsigned int* __restrict__ kvA,
    float* __restrict__ aoA,
    const unsigned int* __restrict__ qB, const unsigned int* __restrict__ kvB,
    float* __restrict__ aoB,
    const float* __restrict__ biasT) {
  __shared__ __align__(16) unsigned short Ks[576*16];   // [key][d]  18432B
  __shared__ __align__(16) unsigned short Vt[16*KPAD];  // [d][key-permuted] 18688B

  const unsigned int* q  = blockIdx.y ? qB  : qA;
  const unsigned int* kv = blockIdx.y ? kvB : kvA;
  float* ao              = blockIdx.y ? aoB : aoA;

  // XCD swizzle: contiguous window stripes per XCD for kv-overlap L2 reuse
  int id = blockIdx.x;                       // 0..511
  int lin = ((id & 7) << 6) | (id >> 3);
  int wi = lin >> 1, hd = lin & 1;
  int wy = wi >> 4, wx = wi & 15;
  int t = threadIdx.x;
  int by = wy*16 - 4, bx = wx*16 - 4;
  int krow = hd*8, vrow = 16 + hd*8;         // packed word-row bases

  int wave = t >> 6, lane = t & 63;
  int quad = lane >> 4, l16 = lane & 15;
  const bf8 zero8 = {0,0,0,0,0,0,0,0};

  // --- Q fragments: 4 packed dword loads each (pre-scaled bf16 in memory)
  bf8 qf[4];
#pragma unroll
  for (int qi = 0; qi < 4; qi++) {
    if (quad < 2) {
      int qt = wave*4 + qi;
      int prow = (wy*16 + qt)*256 + wx*16 + l16;
      union { unsigned int u[4]; bf8 v; } Q;
#pragma unroll
      for (int jw = 0; jw < 4; jw++)
        Q.u[jw] = q[(krow + quad*4 + jw)*HW + prow];
      qf[qi] = Q.v;
    } else {
      qf[qi] = zero8;
    }
  }

  // --- stage K (row-major) and V (transposed, slot-permuted)
  for (int e = t; e < 576; e += 256) {
    int dy = e / 24, dx = e - dy*24;
    int yy = by + dy, xx = bx + dx;
    bool ok = ((unsigned)yy < 256u) && ((unsigned)xx < 256u);
    int pp = yy*256 + xx;
    int off = e & 31;
    int ppos = ((off & 12) << 1) + ((off >> 4) << 2) + (off & 3);
    int vcol = (e & ~31) + ppos;
    unsigned int kwd[8];
#pragma unroll
    for (int i = 0; i < 8; i++) kwd[i] = ok ? kv[(krow + i)*HW + pp] : 0u;
    *(uint4*)&Ks[e*16]     = *(const uint4*)&kwd[0];
    *(uint4*)&Ks[e*16 + 8] = *(const uint4*)&kwd[4];
#pragma unroll
    for (int i = 0; i < 8; i++) {
      unsigned int vw = ok ? kv[(vrow + i)*HW + pp] : 0u;
      Vt[(2*i)*KPAD + vcol]   = (unsigned short)vw;
      Vt[(2*i+1)*KPAD + vcol] = (unsigned short)(vw >> 16);
    }
  }
  __syncthreads();

  f4 oacc[4];
  float lr[4];
  const float* bb[4];
#pragma unroll
  for (int qi = 0; qi < 4; qi++) {
    int qt = wave*4 + qi;
    oacc[qi] = (f4){0.f,0.f,0.f,0.f};
    lr[qi] = 0.f;
    bb[qi] = biasT + (hd*16 + qt)*9216 + quad*64 + l16*4;
  }

#pragma unroll 2
  for (int kt2 = 0; kt2 < 18; kt2++) {
    int k0 = kt2 * 32;
    bf8 kf0 = zero8, kf1 = zero8;
    if (quad < 2) {
      kf0 = *(const bf8*)&Ks[(k0 + l16)*16 + quad*8];
      kf1 = *(const bf8*)&Ks[(k0 + 16 + l16)*16 + quad*8];
    }
    bf8 vf = *(const bf8*)&Vt[l16*KPAD + k0 + quad*8];
    __builtin_amdgcn_s_setprio(1);
#pragma unroll
    for (int qi = 0; qi < 4; qi++) {
      f4 b0 = *(const f4*)&bb[qi][k0*16];
      f4 b1 = *(const f4*)&bb[qi][(k0+16)*16];
      f4 s0 = __builtin_amdgcn_mfma_f32_16x16x32_bf16(kf0, qf[qi], b0, 0, 0, 0);
      f4 s1 = __builtin_amdgcn_mfma_f32_16x16x32_bf16(kf1, qf[qi], b1, 0, 0, 0);
      float p0[4], p1[4];
#pragma unroll
      for (int r = 0; r < 4; r++) {
        p0[r] = ex2(s0[r]);
        p1[r] = ex2(s1[r]);
        lr[qi] += p0[r] + p1[r];
      }
      union { unsigned int u[4]; bf8 v; } P;
      P.u[0] = pk2(p0[0], p0[1]); P.u[1] = pk2(p0[2], p0[3]);
      P.u[2] = pk2(p1[0], p1[1]); P.u[3] = pk2(p1[2], p1[3]);
      oacc[qi] = __builtin_amdgcn_mfma_f32_16x16x32_bf16(P.v, vf, oacc[qi], 0, 0, 0);
    }
    __builtin_amdgcn_s_setprio(0);
  }
#pragma unroll
  for (int qi = 0; qi < 4; qi++) {
    lr[qi] += __shfl_xor(lr[qi], 16, 64);
    lr[qi] += __shfl_xor(lr[qi], 32, 64);
  }
#pragma unroll
  for (int qi = 0; qi < 4; qi++) {
    int qt = wave*4 + qi;
#pragma unroll
    for (int r = 0; r < 4; r++) {
      float lv = __shfl(lr[qi], quad*4 + r, 64);
      int qw = qt*16 + quad*4 + r;
      ao[(hd*16 + l16)*HW + (wy*16 + (qw >> 4))*256 + wx*16 + (qw & 15)] = oacc[qi][r] / lv;
    }
  }
}

// ---------------- proj+shortcut+LN+MLP, ONE ocab per block (proven, no spill) ----------------
__global__ __launch_bounds__(256) void k_projmlp(
    const float* __restrict__ ao1, const float* __restrict__ ao2,
    const float* __restrict__ x, const float* __restrict__ t4,
    const float* __restrict__ part,
    const float* __restrict__ ig, const float* __restrict__ ib,
    const float* __restrict__ wp, const float* __restrict__ bp,
    const float* __restrict__ n2g, const float* __restrict__ n2b,
    const float* __restrict__ mw1, const float* __restrict__ mb1,
    const float* __restrict__ mw2, const float* __restrict__ mb2,
    float* __restrict__ o1, float* __restrict__ o2, int obase) {
  int oc = blockIdx.y + obase;
  const float* ao = oc ? ao2 : ao1;
  float* dst      = oc ? o2  : o1;
  __shared__ __align__(16) float wps[1024];
  __shared__ __align__(16) float w1s[2048];
  __shared__ __align__(16) float w2s[2048];
  __shared__ float bps[32], b1s[64], b2s[32], gs[32], bs[32], as[32], bbs[32];
  int t = threadIdx.x;
  for (int i = t; i < 1024; i += 256) wps[i] = wp[i];
  for (int i = t; i < 2048; i += 256) { w1s[i] = mw1[i]; w2s[i] = mw2[i]; }
  if (t < 64) b1s[t] = mb1[t];
  if (t < 32) {
    bps[t] = bp[t]; b2s[t] = mb2[t]; gs[t] = n2g[t]; bs[t] = n2b[t];
    float s = 0.f, ss = 0.f;
#pragma unroll
    for (int k = 0; k < 16; k++) { s += part[t*16+k]; ss += part[512 + t*16+k]; }
    float m = s * (1.f/65536.f);
    float var = ss * (1.f/65536.f) - m*m;
    float a = rsqrtf(var + 1e-5f) * ig[t];
    as[t] = a; bbs[t] = ib[t] - m*a;
  }
  __syncthreads();
  int p = blockIdx.x*256 + t;
  float acc[32];
#pragma unroll
  for (int j = 0; j < 32; j++) acc[j] = bps[j];
#pragma unroll
  for (int c = 0; c < 32; c++) {
    float vc = ao[c*HW+p];
    const float4* w4 = (const float4*)&wps[c*32];
#pragma unroll
    for (int j4 = 0; j4 < 8; j4++) {
      float4 w = w4[j4];
      acc[j4*4+0] += vc*w.x; acc[j4*4+1] += vc*w.y;
      acc[j4*4+2] += vc*w.z; acc[j4*4+3] += vc*w.w;
    }
  }
  if (oc == 0) {
#pragma unroll
    for (int j = 0; j < 32; j++) acc[j] += x[j*HW+p];
  } else {
#pragma unroll
    for (int j = 0; j < 32; j++) acc[j] += t4[j*HW+p]*as[j] + bbs[j];
  }
  float s = 0.f;
#pragma unroll
  for (int j = 0; j < 32; j++) s += acc[j];
  float m = s * 0.03125f;
  float ss = 0.f;
#pragma unroll
  for (int j = 0; j < 32; j++) { float d = acc[j]-m; ss += d*d; }
  float rs = rsqrtf(ss*0.03125f + 1e-5f);
  float r[32];
#pragma unroll
  for (int j = 0; j < 32; j++) r[j] = b2s[j];
#pragma unroll 1
  for (int half = 0; half < 2; half++) {
    float h[32];
#pragma unroll
    for (int k = 0; k < 32; k++) h[k] = b1s[half*32 + k];
#pragma unroll
    for (int c = 0; c < 32; c++) {
      float ln = (acc[c] - m) * rs * gs[c] + bs[c];
      const float4* w4 = (const float4*)&w1s[c*64 + half*32];
#pragma unroll
      for (int k4 = 0; k4 < 8; k4++) {
        float4 w = w4[k4];
        h[k4*4+0] += ln*w.x; h[k4*4+1] += ln*w.y; h[k4*4+2] += ln*w.z; h[k4*4+3] += ln*w.w;
      }
    }
#pragma unroll
    for (int k = 0; k < 32; k++) {
      float xx = h[k];
      float u = 0.7978845608f * (xx + 0.044715f*xx*xx*xx);
      float th = 1.f - 2.f/(1.f + __expf(2.f*u));
      h[k] = 0.5f * xx * (1.f + th);
    }
#pragma unroll
    for (int k = 0; k < 32; k++) {
      float hk = h[k];
      const float4* w4 = (const float4*)&w2s[(half*32 + k)*32];
#pragma unroll
      for (int j4 = 0; j4 < 8; j4++) {
        float4 w = w4[j4];
        r[j4*4+0] += hk*w.x; r[j4*4+1] += hk*w.y; r[j4*4+2] += hk*w.z; r[j4*4+3] += hk*w.w;
      }
    }
  }
#pragma unroll
  for (int j = 0; j < 32; j++) dst[j*HW + p] = acc[j] + r[j];
}

// ---------------- final: out = o1 + o2 + x (o1 aliases out) ----------------
__global__ __launch_bounds__(256) void k_final(
    const float* o1, const float* __restrict__ o2,
    const float* __restrict__ x, float* out) {
  int i = blockIdx.x*256 + threadIdx.x;
  float4 a = ((const float4*)o1)[i];
  float4 b = ((const float4*)o2)[i];
  float4 c = ((const float4*)x)[i];
  float4 r;
  r.x = a.x + b.x + c.x; r.y = a.y + b.y + c.y;
  r.z = a.z + b.z + c.z; r.w = a.w + b.w + c.w;
  ((float4*)out)[i] = r;
}

extern "C" void kernel_launch(void* const* d_in, const int* in_sizes, int n_in,
                              void* d_out, int out_size, void* d_ws, size_t ws_size,
                              hipStream_t stream) {
  const float* x    = (const float*)d_in[0];
  const float* depth= (const float*)d_in[1];
  const int*   rpi  = (const int*)d_in[2];
  const float* cw1  = (const float*)d_in[3],  *cb1 = (const float*)d_in[4];
  const float* cw2  = (const float*)d_in[5],  *cb2 = (const float*)d_in[6];
  const float* cw3  = (const float*)d_in[7],  *cb3 = (const float*)d_in[8];
  const float* cw4  = (const float*)d_in[9],  *cb4 = (const float*)d_in[10];
  const float* in_g = (const float*)d_in[11], *in_b = (const float*)d_in[12];
  const float* n1g  = (const float*)d_in[13], *n1b = (const float*)d_in[14];
  const float* wq   = (const float*)d_in[15], *bq  = (const float*)d_in[16];
  const float* wkv  = (const float*)d_in[17], *bkv = (const float*)d_in[18];
  const float* rpb  = (const float*)d_in[19];
  const float* wp   = (const float*)d_in[20], *bp  = (const float*)d_in[21];
  const float* n2g  = (const float*)d_in[22], *n2b = (const float*)d_in[23];
  const float* mw1  = (const float*)d_in[24], *mb1 = (const float*)d_in[25];
  const float* mw2  = (const float*)d_in[26], *mb2 = (const float*)d_in[27];

  float* W   = (float*)d_ws;
  float* o1  = (float*)d_out;

  // workspace layout (floats), total 12878848 = 51.5 MB
  float* t4    = W;                          // 2M
  unsigned int* q1  = (unsigned int*)(W + 2097152);   // 1M words
  unsigned int* q2  = (unsigned int*)(W + 3145728);   // 1M words
  unsigned int* kv1 = (unsigned int*)(W + 4194304);   // 2M words
  unsigned int* kv2 = (unsigned int*)(W + 6291456);   // 2M words
  float* ao1   = W + 8388608;                // 2M
  float* ao2   = W + 10485760;               // 2M
  float* biasT = W + 12582912;               // 294912
  float* part  = W + 12877824;               // 1024
  float* t2 = ao1;                           // 1M used, dead before attn writes ao1
  float* t3 = ao2;                           // 1M used, dead before attn writes ao2
  float* o2 = W + 2097152;                   // aliases q1+q2 (dead after attn)

  // flat misc: stem(256) + bias(1152) + lnmm48 roles 0,1 = 1920 blocks
  k_misc   <<<1920, 256, 0, stream>>>(depth, cw1, cb1, cw2, cb2, t2,
                                      rpi, rpb, biasT,
                                      x, t4, part, in_g, in_b, n1g, n1b,
                                      wq, bq, wkv, bkv, q1, kv1, q2, kv2);
  k_conv3  <<<dim3(256,4), 256, 0, stream>>>(t2, cw3, cb3, t3);
  k_conv4  <<<dim3(256,4), 256, 0, stream>>>(t3, cw4, cb4, t4);
  k_instats1<<<512, 256, 0, stream>>>(t4, part);
  // roles 2,3: src=IN(t4) -> q2, kv1
  k_lnmmB  <<<dim3(256,2), 256, 0, stream>>>(x, t4, part, in_g, in_b, n1g, n1b,
                                             wq, bq, wkv, bkv, q1, kv1, q2, kv2);
  k_attn   <<<dim3(512,2), 256, 0, stream>>>(q1, kv1, ao1, q2, kv2, ao2, biasT);
  k_projmlp<<<dim3(256,2), 256, 0, stream>>>(ao1, ao2, x, t4, part, in_g, in_b,
                                             wp, bp, n2g, n2b, mw1, mb1, mw2, mb2,
                                             o1, o2, 0);
  k_final  <<<2048, 256, 0, stream>>>(o1, o2, x, o1);
}